// Round 6
// baseline (711.336 us; speedup 1.0000x reference)
//
#include <hip/hip_runtime.h>
#include <hip/hip_bf16.h>

typedef unsigned int uint;
typedef unsigned short ushort;

#define NN 65536
#define NE 1048576
#define DD 128
#define TOTE (NE + NN)   // 1114112

__device__ __forceinline__ float b2f(ushort u) {
    uint v = ((uint)u) << 16; float f; __builtin_memcpy(&f, &v, 4); return f;
}
__device__ __forceinline__ ushort f2b(float f) {
    uint x; __builtin_memcpy(&x, &f, 4);
    uint r = (x + 0x7fffu + ((x >> 16) & 1u)) >> 16;
    return (ushort)r;
}

typedef __bf16 bf16x8 __attribute__((ext_vector_type(8)));
typedef float f32x4 __attribute__((ext_vector_type(4)));

// ---------- mean of edge_attr ----------
__global__ void k_sum(const float* __restrict__ ea, float* __restrict__ sum) {
    __shared__ float red[256];
    int t = threadIdx.x;
    float s = 0.f;
    for (int i = blockIdx.x * 256 + t; i < NE; i += gridDim.x * 256) s += ea[i];
    red[t] = s; __syncthreads();
    for (int o = 128; o > 0; o >>= 1) { if (t < o) red[t] += red[t + o]; __syncthreads(); }
    if (t == 0) atomicAdd(sum, red[0]);
}

// ---------- CSR build ----------
__global__ void k_hist(const int* __restrict__ dst, int* __restrict__ cnt) {
    int e = blockIdx.x * 256 + threadIdx.x;
    int d = (e < NE) ? dst[e] : (e - NE);
    atomicAdd(&cnt[d], 1);
}

__global__ void k_scanA(const int* __restrict__ cnt, int* __restrict__ row_off, int* __restrict__ bsum) {
    __shared__ int tmp[256];
    int t = threadIdx.x, i = blockIdx.x * 256 + t;
    int v = cnt[i]; tmp[t] = v; __syncthreads();
    for (int off = 1; off < 256; off <<= 1) {
        int x = (t >= off) ? tmp[t - off] : 0;
        __syncthreads();
        tmp[t] += x;
        __syncthreads();
    }
    row_off[i] = tmp[t] - v;
    if (t == 255) bsum[blockIdx.x] = tmp[255];
}

__global__ void k_scanB(int* __restrict__ bsum) {
    __shared__ int tmp[256];
    int t = threadIdx.x;
    int v = bsum[t]; tmp[t] = v; __syncthreads();
    for (int off = 1; off < 256; off <<= 1) {
        int x = (t >= off) ? tmp[t - off] : 0;
        __syncthreads();
        tmp[t] += x;
        __syncthreads();
    }
    bsum[t] = tmp[t] - v;
}

__global__ void k_scanC(int* __restrict__ row_off, const int* __restrict__ bsum, int* __restrict__ cursor) {
    int i = blockIdx.x * 256 + threadIdx.x;
    int v = row_off[i] + bsum[blockIdx.x];
    row_off[i] = v;
    cursor[i] = v;
    if (i == 0) row_off[NN] = TOTE;
}

__global__ void k_scatter(const int* __restrict__ src, const int* __restrict__ dst,
                          const float* __restrict__ ea, const float* __restrict__ sum,
                          int* __restrict__ cursor, int2* __restrict__ adj) {
    int e = blockIdx.x * 256 + threadIdx.x;
    int s, d; float a;
    if (e < NE) { s = src[e]; d = dst[e]; a = ea[e]; }
    else        { s = e - NE; d = s;      a = sum[0] * (1.0f / NE); }
    int pos = atomicAdd(&cursor[d], 1);
    adj[pos] = make_int2(s, __float_as_int(a));
}

// ---------- all layers: transpose W (fp32 k-major -> bf16 n-major) ----------
__global__ void k_transpose(const float* __restrict__ Wl, const float* __restrict__ Wr,
                            ushort* __restrict__ WT) {
    // grid (128, 2, 3), block 128
    int k = blockIdx.x, n = threadIdx.x, lr = blockIdx.y, layer = blockIdx.z;
    const float* W = (lr ? Wr : Wl) + layer * 16384;
    WT[(layer * 2 + lr) * 16384 + n * 128 + k] = f2b(W[k * 128 + n]);
}

// ---------- dual GEMM: xl = src@Wl + bl, xr = src@Wr + br  (bf16 MFMA 16x16x32) ----------
#define LDA 136   // bf16 elems per A row in LDS (272B stride, 16B aligned)

template<bool F32SRC>
__global__ __launch_bounds__(256) void k_gemm(const void* __restrict__ srcv, const ushort* __restrict__ WT,
                                              const float* __restrict__ bl, const float* __restrict__ br,
                                              ushort* __restrict__ xl, ushort* __restrict__ xr) {
    __shared__ ushort A[64 * LDA];
    int t = threadIdx.x;
    int rowbase = blockIdx.x * 64;

    if (F32SRC) {
        const float* src = (const float*)srcv;
        #pragma unroll
        for (int it = 0; it < 8; it++) {
            int idx = it * 256 + t;          // 2048 chunks of 4 floats
            int r = idx >> 5, cc = (idx & 31) * 4;
            float4 v = *(const float4*)&src[(size_t)(rowbase + r) * 128 + cc];
            ushort4 pk; pk.x = f2b(v.x); pk.y = f2b(v.y); pk.z = f2b(v.z); pk.w = f2b(v.w);
            *(ushort4*)&A[r * LDA + cc] = pk;
        }
    } else {
        const ushort* src = (const ushort*)srcv;
        #pragma unroll
        for (int it = 0; it < 4; it++) {
            int idx = it * 256 + t;          // 1024 chunks of 8 bf16
            int r = idx >> 4, cc = (idx & 15) * 8;
            *(bf16x8*)&A[r * LDA + cc] = *(const bf16x8*)&src[(size_t)(rowbase + r) * 128 + cc];
        }
    }
    __syncthreads();

    int wave = t >> 6, lane = t & 63;
    int row16 = lane & 15, quad = lane >> 4;

    f32x4 accl[8], accr[8];
    for (int i = 0; i < 8; i++) {
        accl[i] = (f32x4){0.f, 0.f, 0.f, 0.f};
        accr[i] = (f32x4){0.f, 0.f, 0.f, 0.f};
    }

    for (int ks = 0; ks < 4; ks++) {
        bf16x8 a = *(const bf16x8*)&A[(wave * 16 + row16) * LDA + ks * 32 + quad * 8];
        for (int tc = 0; tc < 8; tc++) {
            int coln = tc * 16 + row16;                 // B fragment: n = lane&15
            bf16x8 b_l = *(const bf16x8*)&WT[coln * 128 + ks * 32 + quad * 8];
            bf16x8 b_r = *(const bf16x8*)&WT[16384 + coln * 128 + ks * 32 + quad * 8];
            accl[tc] = __builtin_amdgcn_mfma_f32_16x16x32_bf16(a, b_l, accl[tc], 0, 0, 0);
            accr[tc] = __builtin_amdgcn_mfma_f32_16x16x32_bf16(a, b_r, accr[tc], 0, 0, 0);
        }
    }

    for (int tc = 0; tc < 8; tc++) {
        int col = tc * 16 + row16;                      // C/D: col = lane&15
        float bbl = bl[col], bbr = br[col];
        for (int r = 0; r < 4; r++) {
            int row = rowbase + wave * 16 + quad * 4 + r;   // C/D: row = quad*4 + reg
            size_t o = (size_t)row * 128 + col;
            xl[o] = f2b(accl[tc][r] + bbl);
            xr[o] = f2b(accr[tc][r] + bbr);
        }
    }
}

// ---------- fused attention: depth-2 pipelined single-gather + online softmax + LN ----------
// One wave per node. Lane = (p=lane>>3: edge slot, cl=lane&7: 16-ch block).
// Two 8-edge groups in flight; rows gathered once; aggregation in registers.
template<int H, bool FINAL>
__global__ __launch_bounds__(256, 4) void k_attn(
    const ushort* __restrict__ xl, const ushort* __restrict__ xr,
    const int* __restrict__ row_off, const int2* __restrict__ adj,
    const float* __restrict__ We, const float* __restrict__ att,
    const float* __restrict__ bias, const float* __restrict__ ln_g, const float* __restrict__ ln_b,
    const float* __restrict__ hin, float* __restrict__ hout, ushort* __restrict__ hb,
    float* __restrict__ outp)
{
    __shared__ float red_s[4][128];

    int wave = threadIdx.x >> 6, lane = threadIdx.x & 63;
    int n = blockIdx.x * 4 + wave;
    int p = lane >> 3;          // edge slot within 8-edge group
    int cl = lane & 7;          // channel block: ch [16*cl, 16*cl+16)
    int c16 = cl * 16;

    // register caches
    float we[16], at[16], xrl[16];
    #pragma unroll
    for (int k = 0; k < 16; k++) { we[k] = We[c16 + k]; at[k] = att[c16 + k]; }
    {
        bf16x8 r0 = *(const bf16x8*)&xr[(size_t)n * 128 + c16];
        bf16x8 r1 = *(const bf16x8*)&xr[(size_t)n * 128 + c16 + 8];
        #pragma unroll
        for (int k = 0; k < 8; k++) { xrl[k] = (float)r0[k]; xrl[8 + k] = (float)r1[k]; }
    }

    int s0 = row_off[n], s1 = row_off[n + 1];
    int iters = (s1 - s0 + 7) >> 3;     // >= 1 (self-loop)

    float m_run = -1e30f, l_run = 0.f;
    float acc[16];
    #pragma unroll
    for (int k = 0; k < 16; k++) acc[k] = 0.f;

    bf16x8 xa0, xa1, xb0, xb1;
    float ea_a = 0.f, ea_b = 0.f;

    auto LOAD = [&](int it, bf16x8& g0, bf16x8& g1, float& gea) {
        int j = s0 + it * 8 + p;
        int ja = (j < s1) ? j : s0;
        int2 pk = adj[ja];
        gea = (j < s1) ? __int_as_float(pk.y) : 0.f;
        const ushort* rp = &xl[(size_t)pk.x * 128 + c16];
        g0 = *(const bf16x8*)rp;
        g1 = *(const bf16x8*)(rp + 8);
    };

    auto STEP = [&](int it, bf16x8& g0, bf16x8& g1, float& gea) {
        float xf[16];
        #pragma unroll
        for (int k = 0; k < 8; k++) { xf[k] = (float)g0[k]; xf[8 + k] = (float)g1[k]; }
        float ea_c = gea;
        bool valid = (s0 + it * 8 + p) < s1;
        if (it + 2 < iters) LOAD(it + 2, g0, g1, gea);   // refill this pipeline slot

        float s = 0.f;
        #pragma unroll
        for (int k = 0; k < 16; k++) {
            float m = xf[k] + fmaf(ea_c, we[k], xrl[k]);
            m = fmaxf(m, 0.2f * m);             // leaky_relu(0.2)
            s = fmaf(m, at[k], s);
        }
        s += __shfl_xor(s, 1);
        if (H == 1) { s += __shfl_xor(s, 2); s += __shfl_xor(s, 4); }
        if (!valid) s = -1e30f;

        float mc = s;
        mc = fmaxf(mc, __shfl_xor(mc, 8));
        mc = fmaxf(mc, __shfl_xor(mc, 16));
        mc = fmaxf(mc, __shfl_xor(mc, 32));
        float nm = fmaxf(m_run, mc);
        float corr = __expf(m_run - nm);
        m_run = nm;
        float e = __expf(s - nm);                // 0 for invalid
        l_run = l_run * corr + e;
        #pragma unroll
        for (int k = 0; k < 16; k++) acc[k] = fmaf(acc[k], corr, e * xf[k]);
    };

    LOAD(0, xa0, xa1, ea_a);
    if (iters > 1) LOAD(1, xb0, xb1, ea_b);

    int it = 0;
    for (; it + 1 < iters; it += 2) {
        STEP(it, xa0, xa1, ea_a);
        STEP(it + 1, xb0, xb1, ea_b);
    }
    if (it < iters) STEP(it, xa0, xa1, ea_a);

    // reduce l and acc over the 8 edge slots (p)
    l_run += __shfl_xor(l_run, 8);
    l_run += __shfl_xor(l_run, 16);
    l_run += __shfl_xor(l_run, 32);
    float inv = 1.0f / (l_run + 1e-16f);
    #pragma unroll
    for (int k = 0; k < 16; k++) {
        acc[k] += __shfl_xor(acc[k], 8);
        acc[k] += __shfl_xor(acc[k], 16);
        acc[k] += __shfl_xor(acc[k], 32);
    }

    // redistribute to 2-channels-per-lane layout via LDS (within-wave)
    if (p == 0) {
        #pragma unroll
        for (int k = 0; k < 16; k += 2)
            *(float2*)&red_s[wave][c16 + k] = make_float2(acc[k] * inv, acc[k + 1] * inv);
    }
    int c0 = 2 * lane;
    float2 ov = *(float2*)&red_s[wave][c0];
    float o0 = ov.x + bias[c0];
    float o1 = ov.y + bias[c0 + 1];

    // LayerNorm over 128 channels (2 per lane)
    float sred = o0 + o1;
    #pragma unroll
    for (int off = 1; off < 64; off <<= 1) sred += __shfl_xor(sred, off);
    float mu = sred * (1.f / 128.f);
    float d0 = o0 - mu, d1 = o1 - mu;
    float v = d0 * d0 + d1 * d1;
    #pragma unroll
    for (int off = 1; off < 64; off <<= 1) v += __shfl_xor(v, off);
    float rstd = rsqrtf(v * (1.f / 128.f) + 1e-5f);
    o0 = d0 * rstd * ln_g[c0] + ln_b[c0];
    o1 = d1 * rstd * ln_g[c0 + 1] + ln_b[c0 + 1];

    float2 hv = *(const float2*)&hin[(size_t)n * 128 + c0];
    if (FINAL) {
        float r0 = hv.x + o0, r1 = hv.y + o1;
        int g = n >> 9, rr = n & 511;
        if (rr < 511)
            *(float2*)&outp[((size_t)(g * 511 + rr)) * 128 + c0] = make_float2(r0, r1);
    } else {
        o0 = 0.5f * o0 * (1.f + erff(o0 * 0.70710678118f));   // exact GELU
        o1 = 0.5f * o1 * (1.f + erff(o1 * 0.70710678118f));
        hv.x += o0; hv.y += o1;
        *(float2*)&hout[(size_t)n * 128 + c0] = hv;
        uint pk = (uint)f2b(hv.x) | ((uint)f2b(hv.y) << 16);
        *(uint*)&hb[(size_t)n * 128 + c0] = pk;
    }
}

extern "C" void kernel_launch(void* const* d_in, const int* in_sizes, int n_in,
                              void* d_out, int out_size, void* d_ws, size_t ws_size,
                              hipStream_t stream) {
    const float* x        = (const float*)d_in[0];
    const int*   edge_src = (const int*)d_in[1];
    const int*   edge_dst = (const int*)d_in[2];
    const float* edge_attr= (const float*)d_in[3];
    const float* Wl       = (const float*)d_in[4];
    const float* bl       = (const float*)d_in[5];
    const float* Wr       = (const float*)d_in[6];
    const float* br       = (const float*)d_in[7];
    const float* We       = (const float*)d_in[8];
    const float* att      = (const float*)d_in[9];
    const float* bias_p   = (const float*)d_in[10];
    const float* ln_g     = (const float*)d_in[11];
    const float* ln_b     = (const float*)d_in[12];
    float* out = (float*)d_out;

    char* ws = (char*)d_ws;
    float*  h       = (float*)(ws + 0);                 // 33,554,432
    ushort* hb      = (ushort*)(ws + 33554432);         // 16,777,216
    ushort* xl      = (ushort*)(ws + 50331648);         // 16,777,216
    ushort* xr      = (ushort*)(ws + 67108864);         // 16,777,216
    int2*   adj     = (int2*)(ws + 83886080);           //  8,912,896
    int*    row_off = (int*)(ws + 92798976);            //    262,400 (incl pad)
    int*    cnt     = (int*)(ws + 93061376);            //    262,144 (also cursor)
    int*    bsum    = (int*)(ws + 93323520);            //      1,024
    float*  sumbuf  = (float*)(ws + 93324544);          //        256
    ushort* WT      = (ushort*)(ws + 93324800);         //    196,608 (3 layers x 2)

    hipMemsetAsync(cnt, 0, NN * sizeof(int), stream);
    hipMemsetAsync(sumbuf, 0, sizeof(float), stream);
    k_sum<<<256, 256, 0, stream>>>(edge_attr, sumbuf);

    // CSR by dst (edges + self loops)
    k_hist<<<TOTE / 256, 256, 0, stream>>>(edge_dst, cnt);
    k_scanA<<<NN / 256, 256, 0, stream>>>(cnt, row_off, bsum);
    k_scanB<<<1, 256, 0, stream>>>(bsum);
    k_scanC<<<NN / 256, 256, 0, stream>>>(row_off, bsum, cnt);
    k_scatter<<<TOTE / 256, 256, 0, stream>>>(edge_src, edge_dst, edge_attr, sumbuf, cnt, adj);

    // weights for all 3 layers
    k_transpose<<<dim3(128, 2, 3), 128, 0, stream>>>(Wl, Wr, WT);

    // layer 0: GEMM from fp32 x; residual from x
    k_gemm<true><<<NN / 64, 256, 0, stream>>>(x, WT, bl, br, xl, xr);
    k_attn<4, false><<<NN / 4, 256, 0, stream>>>(xl, xr, row_off, adj,
                                                 We, att, bias_p, ln_g, ln_b,
                                                 x, h, hb, nullptr);
    // layer 1
    k_gemm<false><<<NN / 64, 256, 0, stream>>>(hb, WT + 32768, bl + 128, br + 128, xl, xr);
    k_attn<4, false><<<NN / 4, 256, 0, stream>>>(xl, xr, row_off, adj,
                                                 We + 128, att + 128, bias_p + 128,
                                                 ln_g + 128, ln_b + 128,
                                                 h, h, hb, nullptr);
    // layer 2 (final): writes out directly, drops virtual node
    k_gemm<false><<<NN / 64, 256, 0, stream>>>(hb, WT + 65536, bl + 256, br + 256, xl, xr);
    k_attn<1, true><<<NN / 4, 256, 0, stream>>>(xl, xr, row_off, adj,
                                                We + 256, att + 256, bias_p + 256,
                                                ln_g + 256, ln_b + 256,
                                                h, nullptr, nullptr, out);
}

// Round 7
// 662.754 us; speedup vs baseline: 1.0733x; 1.0733x over previous
//
#include <hip/hip_runtime.h>
#include <hip/hip_bf16.h>

typedef unsigned int uint;
typedef unsigned short ushort;

#define NN 65536
#define NE 1048576
#define DD 128
#define TOTE (NE + NN)   // 1114112

__device__ __forceinline__ float b2f(ushort u) {
    uint v = ((uint)u) << 16; float f; __builtin_memcpy(&f, &v, 4); return f;
}
__device__ __forceinline__ ushort f2b(float f) {
    uint x; __builtin_memcpy(&x, &f, 4);
    uint r = (x + 0x7fffu + ((x >> 16) & 1u)) >> 16;
    return (ushort)r;
}

typedef __bf16 bf16x8 __attribute__((ext_vector_type(8)));
typedef float f32x4 __attribute__((ext_vector_type(4)));

// ---------- mean of edge_attr ----------
__global__ void k_sum(const float* __restrict__ ea, float* __restrict__ sum) {
    __shared__ float red[256];
    int t = threadIdx.x;
    float s = 0.f;
    for (int i = blockIdx.x * 256 + t; i < NE; i += gridDim.x * 256) s += ea[i];
    red[t] = s; __syncthreads();
    for (int o = 128; o > 0; o >>= 1) { if (t < o) red[t] += red[t + o]; __syncthreads(); }
    if (t == 0) atomicAdd(sum, red[0]);
}

// ---------- CSR build ----------
__global__ void k_hist(const int* __restrict__ dst, int* __restrict__ cnt) {
    int e = blockIdx.x * 256 + threadIdx.x;
    int d = (e < NE) ? dst[e] : (e - NE);
    atomicAdd(&cnt[d], 1);
}

__global__ void k_scanA(const int* __restrict__ cnt, int* __restrict__ row_off, int* __restrict__ bsum) {
    __shared__ int tmp[256];
    int t = threadIdx.x, i = blockIdx.x * 256 + t;
    int v = cnt[i]; tmp[t] = v; __syncthreads();
    for (int off = 1; off < 256; off <<= 1) {
        int x = (t >= off) ? tmp[t - off] : 0;
        __syncthreads();
        tmp[t] += x;
        __syncthreads();
    }
    row_off[i] = tmp[t] - v;
    if (t == 255) bsum[blockIdx.x] = tmp[255];
}

__global__ void k_scanB(int* __restrict__ bsum) {
    __shared__ int tmp[256];
    int t = threadIdx.x;
    int v = bsum[t]; tmp[t] = v; __syncthreads();
    for (int off = 1; off < 256; off <<= 1) {
        int x = (t >= off) ? tmp[t - off] : 0;
        __syncthreads();
        tmp[t] += x;
        __syncthreads();
    }
    bsum[t] = tmp[t] - v;
}

__global__ void k_scanC(int* __restrict__ row_off, const int* __restrict__ bsum, int* __restrict__ cursor) {
    int i = blockIdx.x * 256 + threadIdx.x;
    int v = row_off[i] + bsum[blockIdx.x];
    row_off[i] = v;
    cursor[i] = v;
    if (i == 0) row_off[NN] = TOTE;
}

__global__ void k_scatter(const int* __restrict__ src, const int* __restrict__ dst,
                          const float* __restrict__ ea, const float* __restrict__ sum,
                          int* __restrict__ cursor, int2* __restrict__ adj) {
    int e = blockIdx.x * 256 + threadIdx.x;
    int s, d; float a;
    if (e < NE) { s = src[e]; d = dst[e]; a = ea[e]; }
    else        { s = e - NE; d = s;      a = sum[0] * (1.0f / NE); }
    int pos = atomicAdd(&cursor[d], 1);
    adj[pos] = make_int2(s, __float_as_int(a));
}

// ---------- all layers: transpose W (fp32 k-major -> bf16 n-major) ----------
__global__ void k_transpose(const float* __restrict__ Wl, const float* __restrict__ Wr,
                            ushort* __restrict__ WT) {
    // grid (128, 2, 3), block 128
    int k = blockIdx.x, n = threadIdx.x, lr = blockIdx.y, layer = blockIdx.z;
    const float* W = (lr ? Wr : Wl) + layer * 16384;
    WT[(layer * 2 + lr) * 16384 + n * 128 + k] = f2b(W[k * 128 + n]);
}

// ---------- dual GEMM: xl = src@Wl + bl, xr = src@Wr + br  (bf16 MFMA 16x16x32) ----------
#define LDA 136   // bf16 elems per A row in LDS (272B stride, 16B aligned)

template<bool F32SRC>
__global__ __launch_bounds__(256) void k_gemm(const void* __restrict__ srcv, const ushort* __restrict__ WT,
                                              const float* __restrict__ bl, const float* __restrict__ br,
                                              ushort* __restrict__ xl, ushort* __restrict__ xr) {
    __shared__ ushort A[64 * LDA];
    int t = threadIdx.x;
    int rowbase = blockIdx.x * 64;

    if (F32SRC) {
        const float* src = (const float*)srcv;
        #pragma unroll
        for (int it = 0; it < 8; it++) {
            int idx = it * 256 + t;          // 2048 chunks of 4 floats
            int r = idx >> 5, cc = (idx & 31) * 4;
            float4 v = *(const float4*)&src[(size_t)(rowbase + r) * 128 + cc];
            ushort4 pk; pk.x = f2b(v.x); pk.y = f2b(v.y); pk.z = f2b(v.z); pk.w = f2b(v.w);
            *(ushort4*)&A[r * LDA + cc] = pk;
        }
    } else {
        const ushort* src = (const ushort*)srcv;
        #pragma unroll
        for (int it = 0; it < 4; it++) {
            int idx = it * 256 + t;          // 1024 chunks of 8 bf16
            int r = idx >> 4, cc = (idx & 15) * 8;
            *(bf16x8*)&A[r * LDA + cc] = *(const bf16x8*)&src[(size_t)(rowbase + r) * 128 + cc];
        }
    }
    __syncthreads();

    int wave = t >> 6, lane = t & 63;
    int row16 = lane & 15, quad = lane >> 4;

    f32x4 accl[8], accr[8];
    for (int i = 0; i < 8; i++) {
        accl[i] = (f32x4){0.f, 0.f, 0.f, 0.f};
        accr[i] = (f32x4){0.f, 0.f, 0.f, 0.f};
    }

    for (int ks = 0; ks < 4; ks++) {
        bf16x8 a = *(const bf16x8*)&A[(wave * 16 + row16) * LDA + ks * 32 + quad * 8];
        for (int tc = 0; tc < 8; tc++) {
            int coln = tc * 16 + row16;                 // B fragment: n = lane&15
            bf16x8 b_l = *(const bf16x8*)&WT[coln * 128 + ks * 32 + quad * 8];
            bf16x8 b_r = *(const bf16x8*)&WT[16384 + coln * 128 + ks * 32 + quad * 8];
            accl[tc] = __builtin_amdgcn_mfma_f32_16x16x32_bf16(a, b_l, accl[tc], 0, 0, 0);
            accr[tc] = __builtin_amdgcn_mfma_f32_16x16x32_bf16(a, b_r, accr[tc], 0, 0, 0);
        }
    }

    for (int tc = 0; tc < 8; tc++) {
        int col = tc * 16 + row16;                      // C/D: col = lane&15
        float bbl = bl[col], bbr = br[col];
        for (int r = 0; r < 4; r++) {
            int row = rowbase + wave * 16 + quad * 4 + r;   // C/D: row = quad*4 + reg
            size_t o = (size_t)row * 128 + col;
            xl[o] = f2b(accl[tc][r] + bbl);
            xr[o] = f2b(accr[tc][r] + bbr);
        }
    }
}

// ---------- fused attention, single-gather (R5 body): logits + online softmax + reg aggregation ----------
// One wave per node. Lane = (p=lane>>3: edge slot, cl=lane&7: 16-ch block).
// One lookahead group; rows gathered once; aggregation in registers.
template<int H, bool FINAL>
__global__ __launch_bounds__(256, 4) void k_attn(
    const ushort* __restrict__ xl, const ushort* __restrict__ xr,
    const int* __restrict__ row_off, const int2* __restrict__ adj,
    const float* __restrict__ We, const float* __restrict__ att,
    const float* __restrict__ bias, const float* __restrict__ ln_g, const float* __restrict__ ln_b,
    const float* __restrict__ hin, float* __restrict__ hout, ushort* __restrict__ hb,
    float* __restrict__ outp)
{
    __shared__ float red_s[4][128];

    int wave = threadIdx.x >> 6, lane = threadIdx.x & 63;
    int n = blockIdx.x * 4 + wave;
    int p = lane >> 3;          // edge slot within 8-edge group
    int cl = lane & 7;          // channel block: ch [16*cl, 16*cl+16)
    int c16 = cl * 16;

    // register caches
    float we[16], at[16], xrl[16];
    #pragma unroll
    for (int k = 0; k < 16; k++) { we[k] = We[c16 + k]; at[k] = att[c16 + k]; }
    {
        bf16x8 r0 = *(const bf16x8*)&xr[(size_t)n * 128 + c16];
        bf16x8 r1 = *(const bf16x8*)&xr[(size_t)n * 128 + c16 + 8];
        #pragma unroll
        for (int k = 0; k < 8; k++) { xrl[k] = (float)r0[k]; xrl[8 + k] = (float)r1[k]; }
    }

    int s0 = row_off[n], s1 = row_off[n + 1];
    int iters = (s1 - s0 + 7) >> 3;     // >= 1 (self-loop)

    float m_run = -1e30f, l_run = 0.f;
    float acc[16];
    #pragma unroll
    for (int k = 0; k < 16; k++) acc[k] = 0.f;

    // prefetch group 0
    int j0 = s0 + p;
    int ja = (j0 < s1) ? j0 : s0;
    int2 pk0 = adj[ja];
    float ea_n = (j0 < s1) ? __int_as_float(pk0.y) : 0.f;
    bf16x8 nx0 = *(const bf16x8*)&xl[(size_t)pk0.x * 128 + c16];
    bf16x8 nx1 = *(const bf16x8*)&xl[(size_t)pk0.x * 128 + c16 + 8];

    for (int it = 0; it < iters; ++it) {
        bf16x8 x0 = nx0, x1 = nx1;
        float ea_c = ea_n;
        bool valid = (s0 + it * 8 + p) < s1;

        // prefetch next group
        if (it + 1 < iters) {
            int jn = s0 + (it + 1) * 8 + p;
            int jb = (jn < s1) ? jn : s0;
            int2 pk = adj[jb];
            ea_n = (jn < s1) ? __int_as_float(pk.y) : 0.f;
            nx0 = *(const bf16x8*)&xl[(size_t)pk.x * 128 + c16];
            nx1 = *(const bf16x8*)&xl[(size_t)pk.x * 128 + c16 + 8];
        }

        // convert + logit partial over this lane's 16 channels
        float xf[16];
        #pragma unroll
        for (int k = 0; k < 8; k++) { xf[k] = (float)x0[k]; xf[8 + k] = (float)x1[k]; }
        float s = 0.f;
        #pragma unroll
        for (int k = 0; k < 16; k++) {
            float m = xf[k] + fmaf(ea_c, we[k], xrl[k]);
            m = fmaxf(m, 0.2f * m);             // leaky_relu(0.2)
            s = fmaf(m, at[k], s);
        }
        // head reduction across cl lanes of same edge
        s += __shfl_xor(s, 1);
        if (H == 1) { s += __shfl_xor(s, 2); s += __shfl_xor(s, 4); }
        if (!valid) s = -1e30f;

        // per-head max over the 8 edge slots
        float mc = s;
        mc = fmaxf(mc, __shfl_xor(mc, 8));
        mc = fmaxf(mc, __shfl_xor(mc, 16));
        mc = fmaxf(mc, __shfl_xor(mc, 32));
        float nm = fmaxf(m_run, mc);
        float corr = __expf(m_run - nm);
        m_run = nm;
        float e = __expf(s - nm);                // 0 for invalid
        l_run = l_run * corr + e;
        #pragma unroll
        for (int k = 0; k < 16; k++) acc[k] = fmaf(acc[k], corr, e * xf[k]);
    }

    // reduce l and acc over the 8 edge slots (p)
    l_run += __shfl_xor(l_run, 8);
    l_run += __shfl_xor(l_run, 16);
    l_run += __shfl_xor(l_run, 32);
    float inv = 1.0f / (l_run + 1e-16f);
    #pragma unroll
    for (int k = 0; k < 16; k++) {
        acc[k] += __shfl_xor(acc[k], 8);
        acc[k] += __shfl_xor(acc[k], 16);
        acc[k] += __shfl_xor(acc[k], 32);
    }

    // redistribute to 2-channels-per-lane layout via LDS (within-wave)
    if (p == 0) {
        #pragma unroll
        for (int k = 0; k < 16; k += 2)
            *(float2*)&red_s[wave][c16 + k] = make_float2(acc[k] * inv, acc[k + 1] * inv);
    }
    int c0 = 2 * lane;
    float2 ov = *(float2*)&red_s[wave][c0];
    float o0 = ov.x + bias[c0];
    float o1 = ov.y + bias[c0 + 1];

    // LayerNorm over 128 channels (2 per lane)
    float sred = o0 + o1;
    #pragma unroll
    for (int off = 1; off < 64; off <<= 1) sred += __shfl_xor(sred, off);
    float mu = sred * (1.f / 128.f);
    float d0 = o0 - mu, d1 = o1 - mu;
    float v = d0 * d0 + d1 * d1;
    #pragma unroll
    for (int off = 1; off < 64; off <<= 1) v += __shfl_xor(v, off);
    float rstd = rsqrtf(v * (1.f / 128.f) + 1e-5f);
    o0 = d0 * rstd * ln_g[c0] + ln_b[c0];
    o1 = d1 * rstd * ln_g[c0 + 1] + ln_b[c0 + 1];

    float2 hv = *(const float2*)&hin[(size_t)n * 128 + c0];
    if (FINAL) {
        float r0 = hv.x + o0, r1 = hv.y + o1;
        int g = n >> 9, rr = n & 511;
        if (rr < 511)
            *(float2*)&outp[((size_t)(g * 511 + rr)) * 128 + c0] = make_float2(r0, r1);
    } else {
        o0 = 0.5f * o0 * (1.f + erff(o0 * 0.70710678118f));   // exact GELU
        o1 = 0.5f * o1 * (1.f + erff(o1 * 0.70710678118f));
        hv.x += o0; hv.y += o1;
        *(float2*)&hout[(size_t)n * 128 + c0] = hv;
        uint pk = (uint)f2b(hv.x) | ((uint)f2b(hv.y) << 16);
        *(uint*)&hb[(size_t)n * 128 + c0] = pk;
    }
}

extern "C" void kernel_launch(void* const* d_in, const int* in_sizes, int n_in,
                              void* d_out, int out_size, void* d_ws, size_t ws_size,
                              hipStream_t stream) {
    const float* x        = (const float*)d_in[0];
    const int*   edge_src = (const int*)d_in[1];
    const int*   edge_dst = (const int*)d_in[2];
    const float* edge_attr= (const float*)d_in[3];
    const float* Wl       = (const float*)d_in[4];
    const float* bl       = (const float*)d_in[5];
    const float* Wr       = (const float*)d_in[6];
    const float* br       = (const float*)d_in[7];
    const float* We       = (const float*)d_in[8];
    const float* att      = (const float*)d_in[9];
    const float* bias_p   = (const float*)d_in[10];
    const float* ln_g     = (const float*)d_in[11];
    const float* ln_b     = (const float*)d_in[12];
    float* out = (float*)d_out;

    char* ws = (char*)d_ws;
    float*  h       = (float*)(ws + 0);                 // 33,554,432
    ushort* hb      = (ushort*)(ws + 33554432);         // 16,777,216
    ushort* xl      = (ushort*)(ws + 50331648);         // 16,777,216
    ushort* xr      = (ushort*)(ws + 67108864);         // 16,777,216
    int2*   adj     = (int2*)(ws + 83886080);           //  8,912,896
    int*    row_off = (int*)(ws + 92798976);            //    262,400 (incl pad)
    int*    cnt     = (int*)(ws + 93061376);            //    262,144 (also cursor)
    int*    bsum    = (int*)(ws + 93323520);            //      1,024
    float*  sumbuf  = (float*)(ws + 93324544);          //        256
    ushort* WT      = (ushort*)(ws + 93324800);         //    196,608 (3 layers x 2)

    hipMemsetAsync(cnt, 0, NN * sizeof(int), stream);
    hipMemsetAsync(sumbuf, 0, sizeof(float), stream);
    k_sum<<<256, 256, 0, stream>>>(edge_attr, sumbuf);

    // CSR by dst (edges + self loops)
    k_hist<<<TOTE / 256, 256, 0, stream>>>(edge_dst, cnt);
    k_scanA<<<NN / 256, 256, 0, stream>>>(cnt, row_off, bsum);
    k_scanB<<<1, 256, 0, stream>>>(bsum);
    k_scanC<<<NN / 256, 256, 0, stream>>>(row_off, bsum, cnt);
    k_scatter<<<TOTE / 256, 256, 0, stream>>>(edge_src, edge_dst, edge_attr, sumbuf, cnt, adj);

    // weights for all 3 layers
    k_transpose<<<dim3(128, 2, 3), 128, 0, stream>>>(Wl, Wr, WT);

    // layer 0: GEMM from fp32 x; residual from x
    k_gemm<true><<<NN / 64, 256, 0, stream>>>(x, WT, bl, br, xl, xr);
    k_attn<4, false><<<NN / 4, 256, 0, stream>>>(xl, xr, row_off, adj,
                                                 We, att, bias_p, ln_g, ln_b,
                                                 x, h, hb, nullptr);
    // layer 1
    k_gemm<false><<<NN / 64, 256, 0, stream>>>(hb, WT + 32768, bl + 128, br + 128, xl, xr);
    k_attn<4, false><<<NN / 4, 256, 0, stream>>>(xl, xr, row_off, adj,
                                                 We + 128, att + 128, bias_p + 128,
                                                 ln_g + 128, ln_b + 128,
                                                 h, h, hb, nullptr);
    // layer 2 (final): writes out directly, drops virtual node
    k_gemm<false><<<NN / 64, 256, 0, stream>>>(hb, WT + 65536, bl + 256, br + 256, xl, xr);
    k_attn<1, true><<<NN / 4, 256, 0, stream>>>(xl, xr, row_off, adj,
                                                We + 256, att + 256, bias_p + 256,
                                                ln_g + 256, ln_b + 256,
                                                h, nullptr, nullptr, out);
}